// Round 2
// baseline (3690.838 us; speedup 1.0000x reference)
//
#include <hip/hip_runtime.h>
#include <hip/hip_bf16.h>

typedef __hip_bfloat16 bf16;

#define NN 50000
#define EE 800000
// IN=256, EMB1=128, EMB2=64, L1=64

// out[n,j] = act( sum_k A[n,k]*W[j,k] + bias[j] + addin[n,j] )
// block = J threads, grid = N blocks. A: N x K fp32, W: J x K fp32.
template<int K>
__global__ void mm_fused(const float* __restrict__ A, const float* __restrict__ W,
                         const float* __restrict__ addin, const float* __restrict__ bias,
                         float* __restrict__ out, int J, int act) {
    __shared__ float sA[K];
    int n = blockIdx.x;
    for (int k = threadIdx.x; k < K; k += blockDim.x)
        sA[k] = A[n * K + k];
    __syncthreads();
    int j = threadIdx.x;
    if (j >= J) return;
    const float4* w = reinterpret_cast<const float4*>(W + j * K);
    float acc = 0.f;
#pragma unroll
    for (int k4 = 0; k4 < K / 4; k4++) {
        float4 wf = w[k4];
        int k = k4 * 4;
        acc = fmaf(wf.x, sA[k + 0], acc);
        acc = fmaf(wf.y, sA[k + 1], acc);
        acc = fmaf(wf.z, sA[k + 2], acc);
        acc = fmaf(wf.w, sA[k + 3], acc);
    }
    if (bias) acc += bias[j];
    if (addin) acc += addin[n * J + j];
    if (act == 1) acc = acc > 0.f ? acc : 0.2f * acc;       // leaky_relu
    out[n * J + j] = acc;
}

// dst[row[e]*W + j] += src[col[e]*W + j], W power of 2
template<int W>
__global__ void scatter_add_k(const float* __restrict__ src, const int* __restrict__ row,
                              const int* __restrict__ col, float* __restrict__ dst, int E) {
    long long idx = (long long)blockIdx.x * blockDim.x + threadIdx.x;
    long long total = (long long)E * W;
    if (idx >= total) return;
    int e = (int)(idx / W);
    int j = (int)(idx & (W - 1));
    atomicAdd(&dst[(long long)row[e] * W + j], src[(long long)col[e] * W + j]);
}

// z_mu = tanh(agg2 + h@w_root_mu^T + b_mu); z_log_std = tanh(h@w_std^T + b_std); z_std = exp(...)
// block = 64 threads, grid = N
__global__ void z_kernel(const float* __restrict__ h, const float* __restrict__ agg2,
                         const float* __restrict__ w_root_mu, const float* __restrict__ b_mu,
                         const float* __restrict__ w_std, const float* __restrict__ b_std,
                         float* __restrict__ z,
                         float* __restrict__ out_z, float* __restrict__ out_zmu,
                         float* __restrict__ out_zstd) {
    __shared__ float sH[128];
    int n = blockIdx.x;
    int j = threadIdx.x;
    sH[j] = h[n * 128 + j];
    sH[j + 64] = h[n * 128 + j + 64];
    __syncthreads();
    const float4* wm = reinterpret_cast<const float4*>(w_root_mu + j * 128);
    const float4* wsd = reinterpret_cast<const float4*>(w_std + j * 128);
    float am = 0.f, as = 0.f;
#pragma unroll
    for (int k4 = 0; k4 < 32; k4++) {
        int k = k4 * 4;
        float4 a = wm[k4];
        am = fmaf(a.x, sH[k+0], am); am = fmaf(a.y, sH[k+1], am);
        am = fmaf(a.z, sH[k+2], am); am = fmaf(a.w, sH[k+3], am);
        float4 b = wsd[k4];
        as = fmaf(b.x, sH[k+0], as); as = fmaf(b.y, sH[k+1], as);
        as = fmaf(b.z, sH[k+2], as); as = fmaf(b.w, sH[k+3], as);
    }
    am += agg2[n * 64 + j] + b_mu[j];
    as += b_std[j];
    float zmu = tanhf(am);
    float zls = tanhf(as);
    float zstd = expf(zls);
    z[n * 64 + j] = zmu;
    out_z[n * 64 + j] = zmu;
    out_zmu[n * 64 + j] = zmu;
    out_zstd[n * 64 + j] = zstd;
}

__global__ void norm_kernel(const float* __restrict__ z, float* __restrict__ nrm, int N) {
    int n = blockIdx.x * blockDim.x + threadIdx.x;
    if (n >= N) return;
    const float4* p = reinterpret_cast<const float4*>(z + n * 64);
    float s = 0.f;
#pragma unroll
    for (int i = 0; i < 16; i++) {
        float4 v = p[i];
        s += v.x * v.x + v.y * v.y + v.z * v.z + v.w * v.w;
    }
    nrm[n] = fmaxf(sqrtf(s), 1e-8f);
}

__global__ void edge_kernel(const float* __restrict__ z, const float* __restrict__ nrm,
                            const int* __restrict__ row, const int* __restrict__ col,
                            float* __restrict__ out_wmu, int E) {
    int e = blockIdx.x * blockDim.x + threadIdx.x;
    if (e >= E) return;
    int r = row[e], c = col[e];
    const float4* a = reinterpret_cast<const float4*>(z + (long long)r * 64);
    const float4* b = reinterpret_cast<const float4*>(z + (long long)c * 64);
    float s = 0.f;
#pragma unroll
    for (int i = 0; i < 16; i++) {
        float4 av = a[i], bv = b[i];
        s += av.x * bv.x + av.y * bv.y + av.z * bv.z + av.w * bv.w;
    }
    out_wmu[e] = s / (nrm[r] * nrm[c]);
}

// per-node: g1r[n] = g1[n,:] . w_rel_g2 ; groot[n] = g1[n,:] . w_root_g2
__global__ void gate1_kernel(const float* __restrict__ g1, const float* __restrict__ w_rel,
                             const float* __restrict__ w_root,
                             float* __restrict__ g1r, float* __restrict__ groot, int N) {
    int n = blockIdx.x * blockDim.x + threadIdx.x;
    if (n >= N) return;
    const float* p = g1 + n * 64;
    float sr = 0.f, so = 0.f;
#pragma unroll
    for (int k = 0; k < 64; k++) {
        float v = p[k];
        sr = fmaf(v, w_rel[k], sr);
        so = fmaf(v, w_root[k], so);
    }
    g1r[n] = sr;
    groot[n] = so;
}

// gate[n] = agg4[n] + groot[n] + b_g2 ; per-block partial max
__global__ void gate2_max(const float* __restrict__ agg4, const float* __restrict__ groot,
                          const float* __restrict__ b_g2, float* __restrict__ gate,
                          float* __restrict__ pmax, int N) {
    __shared__ float sm[256];
    float b = b_g2[0];
    float m = -3.4e38f;
    for (int n = blockIdx.x * blockDim.x + threadIdx.x; n < N; n += gridDim.x * blockDim.x) {
        float g = agg4[n] + groot[n] + b;
        gate[n] = g;
        m = fmaxf(m, g);
    }
    sm[threadIdx.x] = m;
    __syncthreads();
    for (int s = 128; s > 0; s >>= 1) {
        if (threadIdx.x < s) sm[threadIdx.x] = fmaxf(sm[threadIdx.x], sm[threadIdx.x + s]);
        __syncthreads();
    }
    if (threadIdx.x == 0) pmax[blockIdx.x] = sm[0];
}

__global__ void reduce_max_final(const float* __restrict__ pmax, float* __restrict__ smax) {
    float m = pmax[threadIdx.x];   // 64 threads, 64 partials
    for (int o = 32; o > 0; o >>= 1) m = fmaxf(m, __shfl_down(m, o));
    if (threadIdx.x == 0) smax[0] = m;
}

// pooled_num[j] += sum_n exp(gate[n]-smax)*z[n,j] ; wsum += sum_n exp(gate[n]-smax)
__global__ void pooled_kernel(const float* __restrict__ gate, const float* __restrict__ smax,
                              const float* __restrict__ z, float* __restrict__ pooled_num,
                              float* __restrict__ wsum, int N) {
    int tid = threadIdx.x;           // 256
    int sub = tid >> 6, j = tid & 63;
    float mx = smax[0];
    float acc = 0.f, ws = 0.f;
    for (int n = blockIdx.x * 4 + sub; n < N; n += gridDim.x * 4) {
        float w = expf(gate[n] - mx);
        acc = fmaf(w, z[n * 64 + j], acc);
        if (j == 0) ws += w;
    }
    __shared__ float lp[4][64];
    __shared__ float lw[4];
    lp[sub][j] = acc;
    if (j == 0) lw[sub] = ws;
    __syncthreads();
    if (sub == 0) {
        float t = lp[0][j] + lp[1][j] + lp[2][j] + lp[3][j];
        atomicAdd(&pooled_num[j], t);
        if (j == 0) atomicAdd(wsum, lw[0] + lw[1] + lw[2] + lw[3]);
    }
}

__global__ void final_kernel(const float* __restrict__ pooled_num, const float* __restrict__ wsum,
                             const float* __restrict__ w_cls1, const float* __restrict__ b_cls1,
                             const float* __restrict__ w_cls2, const float* __restrict__ b_cls2,
                             const float* __restrict__ log_std,
                             float* __restrict__ out_y, float* __restrict__ out_wstd) {
    __shared__ float sp[64];
    __shared__ float st[64];
    int j = threadIdx.x;   // 64
    sp[j] = pooled_num[j] / wsum[0];
    __syncthreads();
    float acc = 0.f;
    const float* w = w_cls1 + j * 64;
#pragma unroll
    for (int k = 0; k < 64; k++) acc = fmaf(sp[k], w[k], acc);
    acc += b_cls1[j];
    st[j] = acc > 0.f ? acc : 0.2f * acc;
    __syncthreads();
    if (j == 0) {
        float l0 = b_cls2[0], l1 = b_cls2[1];
        for (int k = 0; k < 64; k++) {
            l0 = fmaf(st[k], w_cls2[k], l0);
            l1 = fmaf(st[k], w_cls2[64 + k], l1);
        }
        float m = fmaxf(l0, l1);
        float e0 = expf(l0 - m), e1 = expf(l1 - m);
        float s = e0 + e1;
        out_y[0] = e0 / s;
        out_y[1] = e1 / s;
        out_wstd[0] = expf(log_std[0]);
    }
}

extern "C" void kernel_launch(void* const* d_in, const int* in_sizes, int n_in,
                              void* d_out, int out_size, void* d_ws, size_t ws_size,
                              hipStream_t stream) {
    const int N = NN, E = EE;
    const float* x        = (const float*)d_in[0];
    const int*   row      = (const int*)d_in[1];
    const int*   col      = (const int*)d_in[2];
    const float* w_rel1   = (const float*)d_in[3];
    const float* w_root1  = (const float*)d_in[4];
    const float* b1       = (const float*)d_in[5];
    const float* w_rel_mu = (const float*)d_in[6];
    const float* w_root_mu= (const float*)d_in[7];
    const float* b_mu     = (const float*)d_in[8];
    const float* w_std    = (const float*)d_in[9];
    const float* b_std    = (const float*)d_in[10];
    const float* w_rel_g1 = (const float*)d_in[11];
    const float* w_root_g1= (const float*)d_in[12];
    const float* b_g1     = (const float*)d_in[13];
    const float* w_rel_g2 = (const float*)d_in[14];
    const float* w_root_g2= (const float*)d_in[15];
    const float* b_g2     = (const float*)d_in[16];
    const float* w_cls1   = (const float*)d_in[17];
    const float* b_cls1   = (const float*)d_in[18];
    const float* w_cls2   = (const float*)d_in[19];
    const float* b_cls2   = (const float*)d_in[20];
    const float* log_std  = (const float*)d_in[21];

    float* out = (float*)d_out;
    const long long OFF_Y    = 0;
    const long long OFF_WMU  = 2;
    const long long OFF_WSTD = 2 + (long long)E;
    const long long OFF_Z    = 3 + (long long)E;
    const long long OFF_ZMU  = OFF_Z + (long long)N * 64;
    const long long OFF_ZSTD = OFF_ZMU + (long long)N * 64;

    // workspace layout (floats) — aliased to stay small (~77 MB)
    float* ws    = (float*)d_ws;
    float* A     = ws;                    // N*128
    float* B     = A + (long long)N * 128;// N*128 (also used as two N*64 halves)
    float* zbuf  = B + (long long)N * 128;// N*64
    float* g1buf = zbuf + (long long)N * 64; // N*64
    float* nrm   = g1buf + (long long)N * 64; // N
    float* gate  = nrm + N;               // N
    float* pmax  = gate + N;              // 64
    float* smax  = pmax + 64;             // 1
    float* pooled= smax + 1;              // 64
    float* wsum  = pooled + 64;           // 1
    float* Bhi   = B + (long long)N * 64; // upper half of B

    // ---- conv1: h = lrelu(segsum(x@w_rel1^T) + x@w_root1^T + b1) ----
    mm_fused<256><<<N, 128, 0, stream>>>(x, w_rel1, nullptr, nullptr, A, 128, 0);
    hipMemsetAsync(B, 0, (size_t)N * 128 * 4, stream);
    scatter_add_k<128><<<(int)(((long long)E * 128 + 255) / 256), 256, 0, stream>>>(A, row, col, B, E);
    mm_fused<256><<<N, 128, 0, stream>>>(x, w_root1, B, b1, A, 128, 1);   // h -> A

    // ---- conv2 + z_log_std ----
    mm_fused<128><<<N, 64, 0, stream>>>(A, w_rel_mu, nullptr, nullptr, B, 64, 0);  // hr -> B(lo)
    hipMemsetAsync(Bhi, 0, (size_t)N * 64 * 4, stream);
    scatter_add_k<64><<<(int)(((long long)E * 64 + 255) / 256), 256, 0, stream>>>(B, row, col, Bhi, E);
    z_kernel<<<N, 64, 0, stream>>>(A, Bhi, w_root_mu, b_mu, w_std, b_std, zbuf,
                                   out + OFF_Z, out + OFF_ZMU, out + OFF_ZSTD);

    // ---- decode: per-edge cosine similarity ----
    norm_kernel<<<(N + 255) / 256, 256, 0, stream>>>(zbuf, nrm, N);
    edge_kernel<<<(E + 255) / 256, 256, 0, stream>>>(zbuf, nrm, row, col, out + OFF_WMU, E);

    // ---- attention pooling: g1 ----
    mm_fused<64><<<N, 64, 0, stream>>>(zbuf, w_rel_g1, nullptr, nullptr, B, 64, 0);
    hipMemsetAsync(Bhi, 0, (size_t)N * 64 * 4, stream);
    scatter_add_k<64><<<(int)(((long long)E * 64 + 255) / 256), 256, 0, stream>>>(B, row, col, Bhi, E);
    mm_fused<64><<<N, 64, 0, stream>>>(zbuf, w_root_g1, Bhi, b_g1, g1buf, 64, 1);

    // ---- gate conv (width 1): uses A[0..N)=g1r, A[N..2N)=groot, A[2N..3N)=agg ----
    gate1_kernel<<<(N + 255) / 256, 256, 0, stream>>>(g1buf, w_rel_g2, w_root_g2, A, A + N, N);
    hipMemsetAsync(A + 2 * (long long)N, 0, (size_t)N * 4, stream);
    scatter_add_k<1><<<(E + 255) / 256, 256, 0, stream>>>(A, row, col, A + 2 * (long long)N, E);

    // ---- softmax over N + pooled ----
    gate2_max<<<64, 256, 0, stream>>>(A + 2 * (long long)N, A + N, b_g2, gate, pmax, N);
    reduce_max_final<<<1, 64, 0, stream>>>(pmax, smax);
    hipMemsetAsync(pooled, 0, 65 * 4, stream);
    pooled_kernel<<<128, 256, 0, stream>>>(gate, smax, zbuf, pooled, wsum, N);

    // ---- classifier + scalars ----
    final_kernel<<<1, 64, 0, stream>>>(pooled, wsum, w_cls1, b_cls1, w_cls2, b_cls2, log_std,
                                       out + OFF_Y, out + OFF_WSTD);
}

// Round 3
// 1057.122 us; speedup vs baseline: 3.4914x; 3.4914x over previous
//
#include <hip/hip_runtime.h>

#define NN 50000
#define EE 800000
// IN=256, EMB1=128, EMB2=64, L1=64

// ---------------- CSR build ----------------
__global__ void hist_k(const int* __restrict__ row, int* __restrict__ deg, int E) {
    int e = blockIdx.x * blockDim.x + threadIdx.x;
    if (e < E) atomicAdd(&deg[row[e]], 1);
}

__global__ __launch_bounds__(1024) void scan_k(const int* __restrict__ deg, int* __restrict__ ptr,
                                               int* __restrict__ cursor, int N) {
    __shared__ int sm[1024];
    int t = threadIdx.x;
    int chunk = (N + 1023) / 1024;
    int lo = t * chunk, hi = lo + chunk; if (hi > N) hi = N;
    int s = 0;
    for (int i = lo; i < hi; i++) s += deg[i];
    sm[t] = s;
    __syncthreads();
    for (int off = 1; off < 1024; off <<= 1) {
        int v = (t >= off) ? sm[t - off] : 0;
        __syncthreads();
        sm[t] += v;
        __syncthreads();
    }
    int run = (t == 0) ? 0 : sm[t - 1];
    for (int i = lo; i < hi; i++) { ptr[i] = run; cursor[i] = run; run += deg[i]; }
    if (t == 1023) ptr[N] = sm[1023];
}

__global__ void place_k(const int* __restrict__ row, const int* __restrict__ col,
                        int* __restrict__ cursor, int* __restrict__ ccol, int E) {
    int e = blockIdx.x * blockDim.x + threadIdx.x;
    if (e >= E) return;
    int p = atomicAdd(&cursor[row[e]], 1);
    ccol[p] = col[e];
}

// ---------------- weight transposes (one kernel) ----------------
// w0,w1: [128,256] ; w2,w3,w4: [64,128] ; w5,w6: [64,64]  -> WT[k*J+j]
__global__ void transpose_all(const float* __restrict__ w0, const float* __restrict__ w1,
                              const float* __restrict__ w2, const float* __restrict__ w3,
                              const float* __restrict__ w4, const float* __restrict__ w5,
                              const float* __restrict__ w6,
                              float* __restrict__ t0, float* __restrict__ t1,
                              float* __restrict__ t2, float* __restrict__ t3,
                              float* __restrict__ t4, float* __restrict__ t5,
                              float* __restrict__ t6) {
    int idx = blockIdx.x * 256 + threadIdx.x;
    if (idx < 32768)      { int o = idx;         int j = o & 127, k = o >> 7; t0[o] = w0[j * 256 + k]; }
    else if (idx < 65536) { int o = idx - 32768; int j = o & 127, k = o >> 7; t1[o] = w1[j * 256 + k]; }
    else if (idx < 73728) { int o = idx - 65536; int j = o & 63,  k = o >> 6; t2[o] = w2[j * 128 + k]; }
    else if (idx < 81920) { int o = idx - 73728; int j = o & 63,  k = o >> 6; t3[o] = w3[j * 128 + k]; }
    else if (idx < 90112) { int o = idx - 81920; int j = o & 63,  k = o >> 6; t4[o] = w4[j * 128 + k]; }
    else if (idx < 94208) { int o = idx - 90112; int j = o & 63,  k = o >> 6; t5[o] = w5[j * 64 + k];  }
    else if (idx < 98304) { int o = idx - 94208; int j = o & 63,  k = o >> 6; t6[o] = w6[j * 64 + k];  }
}

// ---------------- conv1 dual matmul: xr = x@w_rel1^T, xroot = x@w_root1^T ----------------
// K=256, J=128. block 64 threads (each handles 2 consecutive j), 4 nodes per block.
__global__ __launch_bounds__(64) void dual_mm_256(const float* __restrict__ x,
        const float* __restrict__ wtA, const float* __restrict__ wtB,
        float* __restrict__ oA, float* __restrict__ oB) {
    int t = threadIdx.x;
    int n0 = blockIdx.x * 4;
    const float* xp = x + (size_t)n0 * 256;
    const float2* wA = reinterpret_cast<const float2*>(wtA);
    const float2* wB = reinterpret_cast<const float2*>(wtB);
    float2 a0{0,0}, a1{0,0}, a2{0,0}, a3{0,0};
    float2 b0{0,0}, b1{0,0}, b2{0,0}, b3{0,0};
#pragma unroll 4
    for (int k = 0; k < 256; k++) {
        float2 va = wA[k * 64 + t];
        float2 vb = wB[k * 64 + t];
        float x0 = xp[k], x1 = xp[256 + k], x2 = xp[512 + k], x3 = xp[768 + k];
        a0.x = fmaf(x0, va.x, a0.x); a0.y = fmaf(x0, va.y, a0.y);
        a1.x = fmaf(x1, va.x, a1.x); a1.y = fmaf(x1, va.y, a1.y);
        a2.x = fmaf(x2, va.x, a2.x); a2.y = fmaf(x2, va.y, a2.y);
        a3.x = fmaf(x3, va.x, a3.x); a3.y = fmaf(x3, va.y, a3.y);
        b0.x = fmaf(x0, vb.x, b0.x); b0.y = fmaf(x0, vb.y, b0.y);
        b1.x = fmaf(x1, vb.x, b1.x); b1.y = fmaf(x1, vb.y, b1.y);
        b2.x = fmaf(x2, vb.x, b2.x); b2.y = fmaf(x2, vb.y, b2.y);
        b3.x = fmaf(x3, vb.x, b3.x); b3.y = fmaf(x3, vb.y, b3.y);
    }
    float2* pA = reinterpret_cast<float2*>(oA);
    float2* pB = reinterpret_cast<float2*>(oB);
    pA[(size_t)(n0 + 0) * 64 + t] = a0; pA[(size_t)(n0 + 1) * 64 + t] = a1;
    pA[(size_t)(n0 + 2) * 64 + t] = a2; pA[(size_t)(n0 + 3) * 64 + t] = a3;
    pB[(size_t)(n0 + 0) * 64 + t] = b0; pB[(size_t)(n0 + 1) * 64 + t] = b1;
    pB[(size_t)(n0 + 2) * 64 + t] = b2; pB[(size_t)(n0 + 3) * 64 + t] = b3;
}

// ---------------- CSR gather-sum, width 128 (no atomics) ----------------
__global__ __launch_bounds__(128) void agg_k128(const float* __restrict__ src,
        const int* __restrict__ ptr, const int* __restrict__ ccol, float* __restrict__ dst) {
    int r = blockIdx.x, j = threadIdx.x;
    int beg = ptr[r], end = ptr[r + 1];
    float acc = 0.f;
    for (int e = beg; e < end; e++) {
        int c = ccol[e];
        acc += src[(size_t)c * 128 + j];
    }
    dst[(size_t)r * 128 + j] = acc;
}

// ---------------- h-stage: h = lrelu(agg1+xroot+b1); hr=h@w_rel_mu^T, hmu=h@w_root_mu^T, hstd=h@w_std^T
// K=128 -> 3x J=64. block 64 threads, 4 nodes per block.
__global__ __launch_bounds__(64) void hstage_k(const float* __restrict__ agg1,
        const float* __restrict__ xroot, const float* __restrict__ b1,
        const float* __restrict__ wt_rel_mu, const float* __restrict__ wt_root_mu,
        const float* __restrict__ wt_std,
        float* __restrict__ hr, float* __restrict__ hmu, float* __restrict__ hstd) {
    int j = threadIdx.x;
    int n0 = blockIdx.x * 4;
    const float* a = agg1 + (size_t)n0 * 128;
    const float* x = xroot + (size_t)n0 * 128;
    float r0=0,r1=0,r2=0,r3=0, m0=0,m1=0,m2=0,m3=0, s0=0,s1=0,s2=0,s3=0;
#pragma unroll 2
    for (int k = 0; k < 128; k++) {
        float b = b1[k];
        float h0 = a[k]       + x[k]       + b; h0 = h0 > 0.f ? h0 : 0.2f * h0;
        float h1 = a[128 + k] + x[128 + k] + b; h1 = h1 > 0.f ? h1 : 0.2f * h1;
        float h2 = a[256 + k] + x[256 + k] + b; h2 = h2 > 0.f ? h2 : 0.2f * h2;
        float h3 = a[384 + k] + x[384 + k] + b; h3 = h3 > 0.f ? h3 : 0.2f * h3;
        float wr = wt_rel_mu[k * 64 + j];
        float wm = wt_root_mu[k * 64 + j];
        float wsd = wt_std[k * 64 + j];
        r0 = fmaf(h0, wr, r0); r1 = fmaf(h1, wr, r1); r2 = fmaf(h2, wr, r2); r3 = fmaf(h3, wr, r3);
        m0 = fmaf(h0, wm, m0); m1 = fmaf(h1, wm, m1); m2 = fmaf(h2, wm, m2); m3 = fmaf(h3, wm, m3);
        s0 = fmaf(h0, wsd, s0); s1 = fmaf(h1, wsd, s1); s2 = fmaf(h2, wsd, s2); s3 = fmaf(h3, wsd, s3);
    }
    size_t o = (size_t)n0 * 64 + j;
    hr[o] = r0;  hr[o + 64] = r1;  hr[o + 128] = r2;  hr[o + 192] = r3;
    hmu[o] = m0; hmu[o + 64] = m1; hmu[o + 128] = m2; hmu[o + 192] = m3;
    hstd[o] = s0; hstd[o + 64] = s1; hstd[o + 128] = s2; hstd[o + 192] = s3;
}

// ---------------- z-stage: agg(hr) + tanh/exp + outputs + row norm ----------------
__global__ __launch_bounds__(64) void aggz_k(const float* __restrict__ hr,
        const float* __restrict__ hmu, const float* __restrict__ hstd,
        const float* __restrict__ b_mu, const float* __restrict__ b_std,
        const int* __restrict__ ptr, const int* __restrict__ ccol,
        float* __restrict__ z, float* __restrict__ out_z, float* __restrict__ out_zmu,
        float* __restrict__ out_zstd, float* __restrict__ nrm) {
    int r = blockIdx.x, j = threadIdx.x;
    int beg = ptr[r], end = ptr[r + 1];
    float acc = 0.f;
    for (int e = beg; e < end; e++) acc += hr[(size_t)ccol[e] * 64 + j];
    float zmu = tanhf(acc + hmu[(size_t)r * 64 + j] + b_mu[j]);
    float zls = tanhf(hstd[(size_t)r * 64 + j] + b_std[j]);
    float zstd = expf(zls);
    size_t o = (size_t)r * 64 + j;
    z[o] = zmu; out_z[o] = zmu; out_zmu[o] = zmu; out_zstd[o] = zstd;
    float s = zmu * zmu;
    s += __shfl_xor(s, 1); s += __shfl_xor(s, 2); s += __shfl_xor(s, 4);
    s += __shfl_xor(s, 8); s += __shfl_xor(s, 16); s += __shfl_xor(s, 32);
    if (j == 0) nrm[r] = fmaxf(sqrtf(s), 1e-8f);
}

// ---------------- edge cosine: 16 lanes per edge, coalesced 256B row reads ----------------
__global__ __launch_bounds__(256) void edge_k(const float* __restrict__ z, const float* __restrict__ nrm,
        const int* __restrict__ row, const int* __restrict__ col, float* __restrict__ out, int E) {
    int t = threadIdx.x;
    int sub = t >> 4, off = t & 15;
    int e = blockIdx.x * 16 + sub;
    if (e >= E) return;
    int r = row[e], c = col[e];
    const float4* a = reinterpret_cast<const float4*>(z + (size_t)r * 64);
    const float4* b = reinterpret_cast<const float4*>(z + (size_t)c * 64);
    float4 av = a[off], bv = b[off];
    float s = av.x * bv.x + av.y * bv.y + av.z * bv.z + av.w * bv.w;
    s += __shfl_xor(s, 1); s += __shfl_xor(s, 2); s += __shfl_xor(s, 4); s += __shfl_xor(s, 8);
    if (off == 0) out[e] = s / (nrm[r] * nrm[c]);
}

// ---------------- g1 dual matmul: zr = z@w_rel_g1^T, zroot = z@w_root_g1^T (K=64, J=64) ----------------
__global__ __launch_bounds__(64) void dual_mm_64(const float* __restrict__ z,
        const float* __restrict__ wtA, const float* __restrict__ wtB,
        float* __restrict__ oA, float* __restrict__ oB) {
    int j = threadIdx.x;
    int n0 = blockIdx.x * 4;
    const float* zp = z + (size_t)n0 * 64;
    float a0=0,a1=0,a2=0,a3=0, b0=0,b1=0,b2=0,b3=0;
#pragma unroll 4
    for (int k = 0; k < 64; k++) {
        float wa = wtA[k * 64 + j];
        float wb = wtB[k * 64 + j];
        float z0 = zp[k], z1 = zp[64 + k], z2 = zp[128 + k], z3 = zp[192 + k];
        a0 = fmaf(z0, wa, a0); a1 = fmaf(z1, wa, a1); a2 = fmaf(z2, wa, a2); a3 = fmaf(z3, wa, a3);
        b0 = fmaf(z0, wb, b0); b1 = fmaf(z1, wb, b1); b2 = fmaf(z2, wb, b2); b3 = fmaf(z3, wb, b3);
    }
    size_t o = (size_t)n0 * 64 + j;
    oA[o] = a0; oA[o + 64] = a1; oA[o + 128] = a2; oA[o + 192] = a3;
    oB[o] = b0; oB[o + 64] = b1; oB[o + 128] = b2; oB[o + 192] = b3;
}

// ---------------- g1-stage: g1 = lrelu(agg(zr)+zroot+b_g1); g1r = g1.w_rel_g2; groot = g1.w_root_g2
__global__ __launch_bounds__(64) void g1gate_k(const float* __restrict__ zr, const float* __restrict__ zroot,
        const float* __restrict__ b_g1, const float* __restrict__ w_rel_g2,
        const float* __restrict__ w_root_g2,
        const int* __restrict__ ptr, const int* __restrict__ ccol,
        float* __restrict__ g1r, float* __restrict__ groot) {
    int r = blockIdx.x, j = threadIdx.x;
    int beg = ptr[r], end = ptr[r + 1];
    float acc = 0.f;
    for (int e = beg; e < end; e++) acc += zr[(size_t)ccol[e] * 64 + j];
    float g = acc + zroot[(size_t)r * 64 + j] + b_g1[j];
    g = g > 0.f ? g : 0.2f * g;
    float sr = g * w_rel_g2[j];
    float so = g * w_root_g2[j];
    sr += __shfl_xor(sr, 1); sr += __shfl_xor(sr, 2); sr += __shfl_xor(sr, 4);
    sr += __shfl_xor(sr, 8); sr += __shfl_xor(sr, 16); sr += __shfl_xor(sr, 32);
    so += __shfl_xor(so, 1); so += __shfl_xor(so, 2); so += __shfl_xor(so, 4);
    so += __shfl_xor(so, 8); so += __shfl_xor(so, 16); so += __shfl_xor(so, 32);
    if (j == 0) { g1r[r] = sr; groot[r] = so; }
}

// ---------------- gate assembly: gate[r] = agg1d(g1r) + groot[r] + b_g2 ; partial max ----------------
__global__ __launch_bounds__(256) void gateagg_k(const float* __restrict__ g1r,
        const float* __restrict__ groot, const float* __restrict__ b_g2,
        const int* __restrict__ ptr, const int* __restrict__ ccol,
        float* __restrict__ gate, float* __restrict__ pmax, int N) {
    __shared__ float sm[256];
    float b = b_g2[0];
    float m = -3.4e38f;
    for (int r = blockIdx.x * blockDim.x + threadIdx.x; r < N; r += gridDim.x * blockDim.x) {
        float s = 0.f;
        int end = ptr[r + 1];
        for (int e = ptr[r]; e < end; e++) s += g1r[ccol[e]];
        float g = s + groot[r] + b;
        gate[r] = g;
        m = fmaxf(m, g);
    }
    sm[threadIdx.x] = m;
    __syncthreads();
    for (int s2 = 128; s2 > 0; s2 >>= 1) {
        if (threadIdx.x < s2) sm[threadIdx.x] = fmaxf(sm[threadIdx.x], sm[threadIdx.x + s2]);
        __syncthreads();
    }
    if (threadIdx.x == 0) pmax[blockIdx.x] = sm[0];
}

__global__ void reduce_max_final(const float* __restrict__ pmax, float* __restrict__ smax) {
    float m = pmax[threadIdx.x];   // 64 threads, 64 partials
    for (int o = 32; o > 0; o >>= 1) m = fmaxf(m, __shfl_down(m, o));
    if (threadIdx.x == 0) smax[0] = m;
}

__global__ __launch_bounds__(256) void pooled_kernel(const float* __restrict__ gate,
        const float* __restrict__ smax, const float* __restrict__ z,
        float* __restrict__ pooled_num, float* __restrict__ wsum, int N) {
    int tid = threadIdx.x;
    int sub = tid >> 6, j = tid & 63;
    float mx = smax[0];
    float acc = 0.f, ws = 0.f;
    for (int n = blockIdx.x * 4 + sub; n < N; n += gridDim.x * 4) {
        float w = expf(gate[n] - mx);
        acc = fmaf(w, z[(size_t)n * 64 + j], acc);
        if (j == 0) ws += w;
    }
    __shared__ float lp[4][64];
    __shared__ float lw[4];
    lp[sub][j] = acc;
    if (j == 0) lw[sub] = ws;
    __syncthreads();
    if (sub == 0) {
        float t = lp[0][j] + lp[1][j] + lp[2][j] + lp[3][j];
        atomicAdd(&pooled_num[j], t);
        if (j == 0) atomicAdd(wsum, lw[0] + lw[1] + lw[2] + lw[3]);
    }
}

__global__ void final_kernel(const float* __restrict__ pooled_num, const float* __restrict__ wsum,
                             const float* __restrict__ w_cls1, const float* __restrict__ b_cls1,
                             const float* __restrict__ w_cls2, const float* __restrict__ b_cls2,
                             const float* __restrict__ log_std,
                             float* __restrict__ out_y, float* __restrict__ out_wstd) {
    __shared__ float sp[64];
    __shared__ float st[64];
    int j = threadIdx.x;   // 64
    sp[j] = pooled_num[j] / wsum[0];
    __syncthreads();
    float acc = 0.f;
    const float* w = w_cls1 + j * 64;
#pragma unroll
    for (int k = 0; k < 64; k++) acc = fmaf(sp[k], w[k], acc);
    acc += b_cls1[j];
    st[j] = acc > 0.f ? acc : 0.2f * acc;
    __syncthreads();
    if (j == 0) {
        float l0 = b_cls2[0], l1 = b_cls2[1];
        for (int k = 0; k < 64; k++) {
            l0 = fmaf(st[k], w_cls2[k], l0);
            l1 = fmaf(st[k], w_cls2[64 + k], l1);
        }
        float m = fmaxf(l0, l1);
        float e0 = expf(l0 - m), e1 = expf(l1 - m);
        float s = e0 + e1;
        out_y[0] = e0 / s;
        out_y[1] = e1 / s;
        out_wstd[0] = expf(log_std[0]);
    }
}

extern "C" void kernel_launch(void* const* d_in, const int* in_sizes, int n_in,
                              void* d_out, int out_size, void* d_ws, size_t ws_size,
                              hipStream_t stream) {
    const int N = NN, E = EE;
    const float* x        = (const float*)d_in[0];
    const int*   row      = (const int*)d_in[1];
    const int*   col      = (const int*)d_in[2];
    const float* w_rel1   = (const float*)d_in[3];
    const float* w_root1  = (const float*)d_in[4];
    const float* b1       = (const float*)d_in[5];
    const float* w_rel_mu = (const float*)d_in[6];
    const float* w_root_mu= (const float*)d_in[7];
    const float* b_mu     = (const float*)d_in[8];
    const float* w_std    = (const float*)d_in[9];
    const float* b_std    = (const float*)d_in[10];
    const float* w_rel_g1 = (const float*)d_in[11];
    const float* w_root_g1= (const float*)d_in[12];
    const float* b_g1     = (const float*)d_in[13];
    const float* w_rel_g2 = (const float*)d_in[14];
    const float* w_root_g2= (const float*)d_in[15];
    const float* b_g2     = (const float*)d_in[16];
    const float* w_cls1   = (const float*)d_in[17];
    const float* b_cls1   = (const float*)d_in[18];
    const float* w_cls2   = (const float*)d_in[19];
    const float* b_cls2   = (const float*)d_in[20];
    const float* log_std  = (const float*)d_in[21];

    float* out = (float*)d_out;
    const long long OFF_WMU  = 2;
    const long long OFF_WSTD = 2 + (long long)E;
    const long long OFF_Z    = 3 + (long long)E;
    const long long OFF_ZMU  = OFF_Z + (long long)N * 64;
    const long long OFF_ZSTD = OFF_ZMU + (long long)N * 64;

    // ---- workspace layout (floats), ~94.6 MB total ----
    float* ws = (float*)d_ws;
    float* R0   = ws;                              // N*128 : xr     -> later hr(lo), hmu(hi)
    float* R1   = R0 + (size_t)N * 128;            // N*128 : xroot  -> later zr(lo), zroot(hi)
    float* R2   = R1 + (size_t)N * 128;            // N*128 : agg1   -> later z(lo)
    float* R3   = R2 + (size_t)N * 128;            // N*64  : hstd
    float* R4   = R3 + (size_t)N * 64;             // 4N    : nrm, g1r, groot, gate
    float* R5   = R4 + (size_t)4 * N;              // 256   : pmax(64) | smax(1)@64 | pooled(64)@128 | wsum@192
    float* WT   = R5 + 256;                        // 98304 : transposed weights
    float* wt_rel1   = WT;
    float* wt_root1  = wt_rel1 + 32768;
    float* wt_relmu  = wt_root1 + 32768;
    float* wt_rootmu = wt_relmu + 8192;
    float* wt_std    = wt_rootmu + 8192;
    float* wt_relg1  = wt_std + 8192;
    float* wt_rootg1 = wt_relg1 + 4096;
    int*   deg    = (int*)(wt_rootg1 + 4096);      // N
    int*   ptr    = deg + N;                       // N+1 (pad)
    int*   cursor = ptr + N + 64;                  // N
    int*   ccol   = cursor + N;                    // E

    float* xr    = R0;
    float* xroot = R1;
    float* agg1  = R2;
    float* hr    = R0;                  // lo half after xr dead
    float* hmu   = R0 + (size_t)N * 64; // hi half
    float* hstd  = R3;
    float* zbuf  = R2;                  // lo half after agg1 dead
    float* zr    = R1;                  // lo half after xroot dead
    float* zroot = R1 + (size_t)N * 64;
    float* nrm   = R4;
    float* g1r   = R4 + N;
    float* groot = R4 + 2 * (size_t)N;
    float* gate  = R4 + 3 * (size_t)N;
    float* pmax  = R5;
    float* smax  = R5 + 64;
    float* pooled= R5 + 128;
    float* wsum  = R5 + 192;

    // ---- CSR build (shared by all 4 graph convs) ----
    hipMemsetAsync(deg, 0, (size_t)N * 4, stream);
    hist_k<<<(E + 255) / 256, 256, 0, stream>>>(row, deg, E);
    scan_k<<<1, 1024, 0, stream>>>(deg, ptr, cursor, N);
    place_k<<<(E + 255) / 256, 256, 0, stream>>>(row, col, cursor, ccol, E);

    // ---- weight transposes ----
    transpose_all<<<384, 256, 0, stream>>>(w_rel1, w_root1, w_rel_mu, w_root_mu, w_std,
                                           w_rel_g1, w_root_g1,
                                           wt_rel1, wt_root1, wt_relmu, wt_rootmu, wt_std,
                                           wt_relg1, wt_rootg1);

    // ---- conv1 products ----
    dual_mm_256<<<N / 4, 64, 0, stream>>>(x, wt_rel1, wt_root1, xr, xroot);
    agg_k128<<<N, 128, 0, stream>>>(xr, ptr, ccol, agg1);

    // ---- h-stage: h formed on the fly; emit hr/hmu/hstd ----
    hstage_k<<<N / 4, 64, 0, stream>>>(agg1, xroot, b1, wt_relmu, wt_rootmu, wt_std,
                                       hr, hmu, hstd);

    // ---- z-stage (agg + tanh + outputs + norms) ----
    aggz_k<<<N, 64, 0, stream>>>(hr, hmu, hstd, b_mu, b_std, ptr, ccol,
                                 zbuf, out + OFF_Z, out + OFF_ZMU, out + OFF_ZSTD, nrm);

    // ---- per-edge cosine similarity ----
    edge_k<<<(E + 15) / 16, 256, 0, stream>>>(zbuf, nrm, row, col, out + OFF_WMU, E);

    // ---- attention pooling path ----
    dual_mm_64<<<N / 4, 64, 0, stream>>>(zbuf, wt_relg1, wt_rootg1, zr, zroot);
    g1gate_k<<<N, 64, 0, stream>>>(zr, zroot, b_g1, w_rel_g2, w_root_g2, ptr, ccol, g1r, groot);
    gateagg_k<<<64, 256, 0, stream>>>(g1r, groot, b_g2, ptr, ccol, gate, pmax, N);
    reduce_max_final<<<1, 64, 0, stream>>>(pmax, smax);
    hipMemsetAsync(pooled, 0, 65 * 4, stream);
    pooled_kernel<<<128, 256, 0, stream>>>(gate, smax, zbuf, pooled, wsum, N);

    // ---- classifier + scalars ----
    final_kernel<<<1, 64, 0, stream>>>(pooled, wsum, w_cls1, b_cls1, w_cls2, b_cls2, log_std,
                                       out, out + OFF_WSTD);
}

// Round 4
// 776.731 us; speedup vs baseline: 4.7518x; 1.3610x over previous
//
#include <hip/hip_runtime.h>

#define NN 50000
#define EE 800000
// IN=256, EMB1=128, EMB2=64, L1=64

// ---------------- CSR build ----------------
__global__ void hist_k(const int* __restrict__ row, int* __restrict__ deg, int E) {
    int e = blockIdx.x * blockDim.x + threadIdx.x;
    if (e < E) atomicAdd(&deg[row[e]], 1);
}

__global__ __launch_bounds__(1024) void scan_k(const int* __restrict__ deg, int* __restrict__ ptr,
                                               int* __restrict__ cursor, int N) {
    __shared__ int sm[1024];
    int t = threadIdx.x;
    int chunk = (N + 1023) / 1024;
    int lo = t * chunk, hi = lo + chunk; if (hi > N) hi = N;
    int s = 0;
    for (int i = lo; i < hi; i++) s += deg[i];
    sm[t] = s;
    __syncthreads();
    for (int off = 1; off < 1024; off <<= 1) {
        int v = (t >= off) ? sm[t - off] : 0;
        __syncthreads();
        sm[t] += v;
        __syncthreads();
    }
    int run = (t == 0) ? 0 : sm[t - 1];
    for (int i = lo; i < hi; i++) { ptr[i] = run; cursor[i] = run; run += deg[i]; }
    if (t == 1023) ptr[N] = sm[1023];
}

__global__ void place_k(const int* __restrict__ row, const int* __restrict__ col,
                        int* __restrict__ cursor, int* __restrict__ ccol, int E) {
    int e = blockIdx.x * blockDim.x + threadIdx.x;
    if (e >= E) return;
    int p = atomicAdd(&cursor[row[e]], 1);
    ccol[p] = col[e];
}

// ---------------- combined k-major weight builds ----------------
// wt1[k*256+j]: j<128 -> w_rel1[j,k], else w_root1[j-128,k]          (256x256)
// wt3[k*192+j]: j<64 -> w_rel_mu ; j<128 -> w_root_mu ; else w_std   (128x192)
// wtg[k*128+j]: j<64 -> w_rel_g1 ; else w_root_g1                    (64x128)
__global__ void transpose_all(const float* __restrict__ w_rel1, const float* __restrict__ w_root1,
                              const float* __restrict__ w_rel_mu, const float* __restrict__ w_root_mu,
                              const float* __restrict__ w_std,
                              const float* __restrict__ w_rel_g1, const float* __restrict__ w_root_g1,
                              float* __restrict__ wt1, float* __restrict__ wt3,
                              float* __restrict__ wtg) {
    int idx = blockIdx.x * 256 + threadIdx.x;
    if (idx < 65536) {
        int j = idx & 255, k = idx >> 8;
        wt1[idx] = (j < 128) ? w_rel1[j * 256 + k] : w_root1[(j - 128) * 256 + k];
    } else if (idx < 90112) {
        int o = idx - 65536; int j = o % 192, k = o / 192;
        wt3[o] = (j < 64) ? w_rel_mu[j * 128 + k]
               : (j < 128) ? w_root_mu[(j - 64) * 128 + k]
                           : w_std[(j - 128) * 128 + k];
    } else if (idx < 98304) {
        int o = idx - 90112; int j = o & 127, k = o >> 7;
        wtg[o] = (j < 64) ? w_rel_g1[j * 64 + k] : w_root_g1[(j - 64) * 64 + k];
    }
}

// ---------------- conv1 GEMM: [xr | xroot] = x @ wt1 ; 8 nodes/block, 4 cols/thread ----------------
__global__ __launch_bounds__(64) void mm256_k(const float* __restrict__ x,
        const float* __restrict__ wt,
        float* __restrict__ xr, float* __restrict__ xroot) {
    int t = threadIdx.x;
    int n0 = blockIdx.x * 8;
    const float* xp = x + (size_t)n0 * 256;
    float a0[8] = {}, a1[8] = {}, a2[8] = {}, a3[8] = {};
#pragma unroll 4
    for (int k = 0; k < 256; k++) {
        const float* wk = wt + k * 256;
        float w0 = wk[t], w1 = wk[t + 64], w2 = wk[t + 128], w3 = wk[t + 192];
#pragma unroll
        for (int n = 0; n < 8; n++) {
            float xv = xp[n * 256 + k];
            a0[n] = fmaf(xv, w0, a0[n]);
            a1[n] = fmaf(xv, w1, a1[n]);
            a2[n] = fmaf(xv, w2, a2[n]);
            a3[n] = fmaf(xv, w3, a3[n]);
        }
    }
#pragma unroll
    for (int n = 0; n < 8; n++) {
        size_t o = (size_t)(n0 + n) * 128;
        xr[o + t]        = a0[n];
        xr[o + t + 64]   = a1[n];
        xroot[o + t]      = a2[n];
        xroot[o + t + 64] = a3[n];
    }
}

// ---------------- CSR gather-sum, width 128, 4-deep MLP ----------------
__global__ __launch_bounds__(128) void agg_k128(const float* __restrict__ src,
        const int* __restrict__ ptr, const int* __restrict__ ccol, float* __restrict__ dst) {
    int r = blockIdx.x, j = threadIdx.x;
    int beg = ptr[r], end = ptr[r + 1];
    float a0 = 0.f, a1 = 0.f, a2 = 0.f, a3 = 0.f;
    int e = beg;
    for (; e + 4 <= end; e += 4) {
        int c0 = ccol[e], c1 = ccol[e + 1], c2 = ccol[e + 2], c3 = ccol[e + 3];
        a0 += src[(size_t)c0 * 128 + j];
        a1 += src[(size_t)c1 * 128 + j];
        a2 += src[(size_t)c2 * 128 + j];
        a3 += src[(size_t)c3 * 128 + j];
    }
    for (; e < end; e++) a0 += src[(size_t)ccol[e] * 128 + j];
    dst[(size_t)r * 128 + j] = (a0 + a1) + (a2 + a3);
}

// ---------------- h = lrelu(agg1 + xroot + b1), elementwise float4 ----------------
__global__ __launch_bounds__(256) void h_k(const float4* __restrict__ agg1,
        const float4* __restrict__ xroot, const float* __restrict__ b1,
        float4* __restrict__ h, int total4) {
    int i = blockIdx.x * 256 + threadIdx.x;
    if (i >= total4) return;
    float4 a = agg1[i], x = xroot[i];
    int k = (i & 31) * 4;
    float4 r;
    r.x = a.x + x.x + b1[k + 0]; r.x = r.x > 0.f ? r.x : 0.2f * r.x;
    r.y = a.y + x.y + b1[k + 1]; r.y = r.y > 0.f ? r.y : 0.2f * r.y;
    r.z = a.z + x.z + b1[k + 2]; r.z = r.z > 0.f ? r.z : 0.2f * r.z;
    r.w = a.w + x.w + b1[k + 3]; r.w = r.w > 0.f ? r.w : 0.2f * r.w;
    h[i] = r;
}

// ---------------- triple matmul: hr|hmu|hstd = h @ wt3 ; 8 nodes/block, 3 cols/thread ----------------
__global__ __launch_bounds__(64) void mm128x3_k(const float* __restrict__ h,
        const float* __restrict__ wt,
        float* __restrict__ hr, float* __restrict__ hmu, float* __restrict__ hstd) {
    int t = threadIdx.x;
    int n0 = blockIdx.x * 8;
    const float* hp = h + (size_t)n0 * 128;
    float a0[8] = {}, a1[8] = {}, a2[8] = {};
#pragma unroll 4
    for (int k = 0; k < 128; k++) {
        const float* wk = wt + k * 192;
        float w0 = wk[t], w1 = wk[t + 64], w2 = wk[t + 128];
#pragma unroll
        for (int n = 0; n < 8; n++) {
            float hv = hp[n * 128 + k];
            a0[n] = fmaf(hv, w0, a0[n]);
            a1[n] = fmaf(hv, w1, a1[n]);
            a2[n] = fmaf(hv, w2, a2[n]);
        }
    }
#pragma unroll
    for (int n = 0; n < 8; n++) {
        size_t o = (size_t)(n0 + n) * 64 + t;
        hr[o] = a0[n]; hmu[o] = a1[n]; hstd[o] = a2[n];
    }
}

// ---------------- z-stage: agg(hr) + tanh/exp + outputs + row norm (4-deep MLP) ----------------
__global__ __launch_bounds__(64) void aggz_k(const float* __restrict__ hr,
        const float* __restrict__ hmu, const float* __restrict__ hstd,
        const float* __restrict__ b_mu, const float* __restrict__ b_std,
        const int* __restrict__ ptr, const int* __restrict__ ccol,
        float* __restrict__ z, float* __restrict__ out_z, float* __restrict__ out_zmu,
        float* __restrict__ out_zstd, float* __restrict__ nrm) {
    int r = blockIdx.x, j = threadIdx.x;
    int beg = ptr[r], end = ptr[r + 1];
    float a0 = 0.f, a1 = 0.f, a2 = 0.f, a3 = 0.f;
    int e = beg;
    for (; e + 4 <= end; e += 4) {
        int c0 = ccol[e], c1 = ccol[e + 1], c2 = ccol[e + 2], c3 = ccol[e + 3];
        a0 += hr[(size_t)c0 * 64 + j];
        a1 += hr[(size_t)c1 * 64 + j];
        a2 += hr[(size_t)c2 * 64 + j];
        a3 += hr[(size_t)c3 * 64 + j];
    }
    for (; e < end; e++) a0 += hr[(size_t)ccol[e] * 64 + j];
    float acc = (a0 + a1) + (a2 + a3);
    float zmu = tanhf(acc + hmu[(size_t)r * 64 + j] + b_mu[j]);
    float zls = tanhf(hstd[(size_t)r * 64 + j] + b_std[j]);
    float zstd = expf(zls);
    size_t o = (size_t)r * 64 + j;
    z[o] = zmu; out_z[o] = zmu; out_zmu[o] = zmu; out_zstd[o] = zstd;
    float s = zmu * zmu;
    s += __shfl_xor(s, 1); s += __shfl_xor(s, 2); s += __shfl_xor(s, 4);
    s += __shfl_xor(s, 8); s += __shfl_xor(s, 16); s += __shfl_xor(s, 32);
    if (j == 0) nrm[r] = fmaxf(sqrtf(s), 1e-8f);
}

// ---------------- edge cosine: 16 lanes per edge ----------------
__global__ __launch_bounds__(256) void edge_k(const float* __restrict__ z, const float* __restrict__ nrm,
        const int* __restrict__ row, const int* __restrict__ col, float* __restrict__ out, int E) {
    int t = threadIdx.x;
    int sub = t >> 4, off = t & 15;
    int e = blockIdx.x * 16 + sub;
    if (e >= E) return;
    int r = row[e], c = col[e];
    const float4* a = reinterpret_cast<const float4*>(z + (size_t)r * 64);
    const float4* b = reinterpret_cast<const float4*>(z + (size_t)c * 64);
    float4 av = a[off], bv = b[off];
    float s = av.x * bv.x + av.y * bv.y + av.z * bv.z + av.w * bv.w;
    s += __shfl_xor(s, 1); s += __shfl_xor(s, 2); s += __shfl_xor(s, 4); s += __shfl_xor(s, 8);
    if (off == 0) out[e] = s / (nrm[r] * nrm[c]);
}

// ---------------- dual matmul: zr|zroot = z @ wtg ; 8 nodes/block, 2 cols/thread ----------------
__global__ __launch_bounds__(64) void mm64x2_k(const float* __restrict__ z,
        const float* __restrict__ wt,
        float* __restrict__ zr, float* __restrict__ zroot) {
    int t = threadIdx.x;
    int n0 = blockIdx.x * 8;
    const float* zp = z + (size_t)n0 * 64;
    float a0[8] = {}, a1[8] = {};
#pragma unroll 4
    for (int k = 0; k < 64; k++) {
        const float* wk = wt + k * 128;
        float w0 = wk[t], w1 = wk[t + 64];
#pragma unroll
        for (int n = 0; n < 8; n++) {
            float zv = zp[n * 64 + k];
            a0[n] = fmaf(zv, w0, a0[n]);
            a1[n] = fmaf(zv, w1, a1[n]);
        }
    }
#pragma unroll
    for (int n = 0; n < 8; n++) {
        size_t o = (size_t)(n0 + n) * 64 + t;
        zr[o] = a0[n]; zroot[o] = a1[n];
    }
}

// ---------------- g1-stage (4-deep MLP) ----------------
__global__ __launch_bounds__(64) void g1gate_k(const float* __restrict__ zr, const float* __restrict__ zroot,
        const float* __restrict__ b_g1, const float* __restrict__ w_rel_g2,
        const float* __restrict__ w_root_g2,
        const int* __restrict__ ptr, const int* __restrict__ ccol,
        float* __restrict__ g1r, float* __restrict__ groot) {
    int r = blockIdx.x, j = threadIdx.x;
    int beg = ptr[r], end = ptr[r + 1];
    float a0 = 0.f, a1 = 0.f, a2 = 0.f, a3 = 0.f;
    int e = beg;
    for (; e + 4 <= end; e += 4) {
        int c0 = ccol[e], c1 = ccol[e + 1], c2 = ccol[e + 2], c3 = ccol[e + 3];
        a0 += zr[(size_t)c0 * 64 + j];
        a1 += zr[(size_t)c1 * 64 + j];
        a2 += zr[(size_t)c2 * 64 + j];
        a3 += zr[(size_t)c3 * 64 + j];
    }
    for (; e < end; e++) a0 += zr[(size_t)ccol[e] * 64 + j];
    float g = (a0 + a1) + (a2 + a3) + zroot[(size_t)r * 64 + j] + b_g1[j];
    g = g > 0.f ? g : 0.2f * g;
    float sr = g * w_rel_g2[j];
    float so = g * w_root_g2[j];
    sr += __shfl_xor(sr, 1); sr += __shfl_xor(sr, 2); sr += __shfl_xor(sr, 4);
    sr += __shfl_xor(sr, 8); sr += __shfl_xor(sr, 16); sr += __shfl_xor(sr, 32);
    so += __shfl_xor(so, 1); so += __shfl_xor(so, 2); so += __shfl_xor(so, 4);
    so += __shfl_xor(so, 8); so += __shfl_xor(so, 16); so += __shfl_xor(so, 32);
    if (j == 0) { g1r[r] = sr; groot[r] = so; }
}

// ---------------- gate assembly + partial max ----------------
__global__ __launch_bounds__(256) void gateagg_k(const float* __restrict__ g1r,
        const float* __restrict__ groot, const float* __restrict__ b_g2,
        const int* __restrict__ ptr, const int* __restrict__ ccol,
        float* __restrict__ gate, float* __restrict__ pmax, int N) {
    __shared__ float sm[256];
    float b = b_g2[0];
    float m = -3.4e38f;
    for (int r = blockIdx.x * blockDim.x + threadIdx.x; r < N; r += gridDim.x * blockDim.x) {
        int beg = ptr[r], end = ptr[r + 1];
        float s0 = 0.f, s1 = 0.f, s2 = 0.f, s3 = 0.f;
        int e = beg;
        for (; e + 4 <= end; e += 4) {
            s0 += g1r[ccol[e]]; s1 += g1r[ccol[e + 1]];
            s2 += g1r[ccol[e + 2]]; s3 += g1r[ccol[e + 3]];
        }
        for (; e < end; e++) s0 += g1r[ccol[e]];
        float g = (s0 + s1) + (s2 + s3) + groot[r] + b;
        gate[r] = g;
        m = fmaxf(m, g);
    }
    sm[threadIdx.x] = m;
    __syncthreads();
    for (int s2 = 128; s2 > 0; s2 >>= 1) {
        if (threadIdx.x < s2) sm[threadIdx.x] = fmaxf(sm[threadIdx.x], sm[threadIdx.x + s2]);
        __syncthreads();
    }
    if (threadIdx.x == 0) pmax[blockIdx.x] = sm[0];
}

__global__ void reduce_max_final(const float* __restrict__ pmax, float* __restrict__ smax) {
    float m = pmax[threadIdx.x];   // 64 threads, 64 partials
    for (int o = 32; o > 0; o >>= 1) m = fmaxf(m, __shfl_down(m, o));
    if (threadIdx.x == 0) smax[0] = m;
}

__global__ __launch_bounds__(256) void pooled_kernel(const float* __restrict__ gate,
        const float* __restrict__ smax, const float* __restrict__ z,
        float* __restrict__ pooled_num, float* __restrict__ wsum, int N) {
    int tid = threadIdx.x;
    int sub = tid >> 6, j = tid & 63;
    float mx = smax[0];
    float acc = 0.f, wsl = 0.f;
    for (int n = blockIdx.x * 4 + sub; n < N; n += gridDim.x * 4) {
        float w = expf(gate[n] - mx);
        acc = fmaf(w, z[(size_t)n * 64 + j], acc);
        if (j == 0) wsl += w;
    }
    __shared__ float lp[4][64];
    __shared__ float lw[4];
    lp[sub][j] = acc;
    if (j == 0) lw[sub] = wsl;
    __syncthreads();
    if (sub == 0) {
        float t = lp[0][j] + lp[1][j] + lp[2][j] + lp[3][j];
        atomicAdd(&pooled_num[j], t);
        if (j == 0) atomicAdd(wsum, lw[0] + lw[1] + lw[2] + lw[3]);
    }
}

__global__ void final_kernel(const float* __restrict__ pooled_num, const float* __restrict__ wsum,
                             const float* __restrict__ w_cls1, const float* __restrict__ b_cls1,
                             const float* __restrict__ w_cls2, const float* __restrict__ b_cls2,
                             const float* __restrict__ log_std,
                             float* __restrict__ out_y, float* __restrict__ out_wstd) {
    __shared__ float sp[64];
    __shared__ float st[64];
    int j = threadIdx.x;   // 64
    sp[j] = pooled_num[j] / wsum[0];
    __syncthreads();
    float acc = 0.f;
    const float* w = w_cls1 + j * 64;
#pragma unroll
    for (int k = 0; k < 64; k++) acc = fmaf(sp[k], w[k], acc);
    acc += b_cls1[j];
    st[j] = acc > 0.f ? acc : 0.2f * acc;
    __syncthreads();
    if (j == 0) {
        float l0 = b_cls2[0], l1 = b_cls2[1];
        for (int k = 0; k < 64; k++) {
            l0 = fmaf(st[k], w_cls2[k], l0);
            l1 = fmaf(st[k], w_cls2[64 + k], l1);
        }
        float m = fmaxf(l0, l1);
        float e0 = expf(l0 - m), e1 = expf(l1 - m);
        float s = e0 + e1;
        out_y[0] = e0 / s;
        out_y[1] = e1 / s;
        out_wstd[0] = expf(log_std[0]);
    }
}

extern "C" void kernel_launch(void* const* d_in, const int* in_sizes, int n_in,
                              void* d_out, int out_size, void* d_ws, size_t ws_size,
                              hipStream_t stream) {
    const int N = NN, E = EE;
    const float* x        = (const float*)d_in[0];
    const int*   row      = (const int*)d_in[1];
    const int*   col      = (const int*)d_in[2];
    const float* w_rel1   = (const float*)d_in[3];
    const float* w_root1  = (const float*)d_in[4];
    const float* b1       = (const float*)d_in[5];
    const float* w_rel_mu = (const float*)d_in[6];
    const float* w_root_mu= (const float*)d_in[7];
    const float* b_mu     = (const float*)d_in[8];
    const float* w_std    = (const float*)d_in[9];
    const float* b_std    = (const float*)d_in[10];
    const float* w_rel_g1 = (const float*)d_in[11];
    const float* w_root_g1= (const float*)d_in[12];
    const float* b_g1     = (const float*)d_in[13];
    const float* w_rel_g2 = (const float*)d_in[14];
    const float* w_root_g2= (const float*)d_in[15];
    const float* b_g2     = (const float*)d_in[16];
    const float* w_cls1   = (const float*)d_in[17];
    const float* b_cls1   = (const float*)d_in[18];
    const float* w_cls2   = (const float*)d_in[19];
    const float* b_cls2   = (const float*)d_in[20];
    const float* log_std  = (const float*)d_in[21];

    float* out = (float*)d_out;
    const long long OFF_WMU  = 2;
    const long long OFF_WSTD = 2 + (long long)E;
    const long long OFF_Z    = 3 + (long long)E;
    const long long OFF_ZMU  = OFF_Z + (long long)N * 64;
    const long long OFF_ZSTD = OFF_ZMU + (long long)N * 64;

    // ---- workspace layout (floats), ~95 MB total ----
    float* wsp = (float*)d_ws;
    float* R0   = wsp;                             // N*128 : xr -> h
    float* R1   = R0 + (size_t)N * 128;            // N*128 : xroot -> [hr | hmu]
    float* R2   = R1 + (size_t)N * 128;            // N*128 : agg1 -> [hstd -> zr | zroot]
    float* R3   = R2 + (size_t)N * 128;            // N*64  : z
    float* R4   = R3 + (size_t)N * 64;             // 4N    : nrm, g1r, groot, gate
    float* R5   = R4 + (size_t)4 * N;              // 256   : pmax | smax | pooled | wsum
    float* wt1  = R5 + 256;                        // 65536
    float* wt3  = wt1 + 65536;                     // 24576
    float* wtg  = wt3 + 24576;                     // 8192
    int*   deg    = (int*)(wtg + 8192);            // N
    int*   ptr    = deg + N;                       // N+1 (pad 64)
    int*   cursor = ptr + N + 64;                  // N
    int*   ccol   = cursor + N;                    // E

    float* xr    = R0;
    float* h     = R0;
    float* xroot = R1;
    float* hr    = R1;
    float* hmu   = R1 + (size_t)N * 64;
    float* agg1  = R2;
    float* hstd  = R2;
    float* zr    = R2;
    float* zroot = R2 + (size_t)N * 64;
    float* zbuf  = R3;
    float* nrm   = R4;
    float* g1r   = R4 + N;
    float* groot = R4 + 2 * (size_t)N;
    float* gate  = R4 + 3 * (size_t)N;
    float* pmax  = R5;
    float* smax  = R5 + 64;
    float* pooled= R5 + 128;
    float* wsum  = R5 + 192;

    // ---- CSR build (shared by all 4 graph convs) ----
    hipMemsetAsync(deg, 0, (size_t)N * 4, stream);
    hist_k<<<(E + 255) / 256, 256, 0, stream>>>(row, deg, E);
    scan_k<<<1, 1024, 0, stream>>>(deg, ptr, cursor, N);
    place_k<<<(E + 255) / 256, 256, 0, stream>>>(row, col, cursor, ccol, E);

    // ---- combined transposed weights ----
    transpose_all<<<384, 256, 0, stream>>>(w_rel1, w_root1, w_rel_mu, w_root_mu, w_std,
                                           w_rel_g1, w_root_g1, wt1, wt3, wtg);

    // ---- conv1 products ----
    mm256_k<<<N / 8, 64, 0, stream>>>(x, wt1, xr, xroot);
    agg_k128<<<N, 128, 0, stream>>>(xr, ptr, ccol, agg1);
    h_k<<<(N * 128 / 4 + 255) / 256, 256, 0, stream>>>(
        (const float4*)agg1, (const float4*)xroot, b1, (float4*)h, N * 128 / 4);

    // ---- conv2 products (h dead-write over xr is safe: h IS R0) ----
    mm128x3_k<<<N / 8, 64, 0, stream>>>(h, wt3, hr, hmu, hstd);

    // ---- z-stage (agg + tanh + outputs + norms) ----
    aggz_k<<<N, 64, 0, stream>>>(hr, hmu, hstd, b_mu, b_std, ptr, ccol,
                                 zbuf, out + OFF_Z, out + OFF_ZMU, out + OFF_ZSTD, nrm);

    // ---- per-edge cosine similarity ----
    edge_k<<<(E + 15) / 16, 256, 0, stream>>>(zbuf, nrm, row, col, out + OFF_WMU, E);

    // ---- attention pooling path ----
    mm64x2_k<<<N / 8, 64, 0, stream>>>(zbuf, wtg, zr, zroot);
    g1gate_k<<<N, 64, 0, stream>>>(zr, zroot, b_g1, w_rel_g2, w_root_g2, ptr, ccol, g1r, groot);
    gateagg_k<<<64, 256, 0, stream>>>(g1r, groot, b_g2, ptr, ccol, gate, pmax, N);
    reduce_max_final<<<1, 64, 0, stream>>>(pmax, smax);
    hipMemsetAsync(pooled, 0, 65 * 4, stream);
    pooled_kernel<<<128, 256, 0, stream>>>(gate, smax, zbuf, pooled, wsum, N);

    // ---- classifier + scalars ----
    final_kernel<<<1, 64, 0, stream>>>(pooled, wsum, w_cls1, b_cls1, w_cls2, b_cls2, log_std,
                                       out, out + OFF_WSTD);
}